// Round 13
// baseline (1281.020 us; speedup 1.0000x reference)
//
#include <hip/hip_runtime.h>
#include <hip/hip_bf16.h>

#define BB 128
#define NN 49
#define VV 10000
#define TT 20

typedef short s8x8 __attribute__((ext_vector_type(8)));
typedef __bf16 bf8x8 __attribute__((ext_vector_type(8)));
typedef float f32x4 __attribute__((ext_vector_type(4)));
typedef unsigned long long ull;

__device__ __forceinline__ float bf2f(short s){ return (float)__builtin_bit_cast(__bf16, s); }
__device__ __forceinline__ short f2bf(float f){ return __builtin_bit_cast(short, (__bf16)f); }

__device__ __forceinline__ s8x8 cast8(const float* p){
  float4 a = *(const float4*)p;
  float4 b = *(const float4*)(p + 4);
  s8x8 r;
  r[0] = f2bf(a.x); r[1] = f2bf(a.y); r[2] = f2bf(a.z); r[3] = f2bf(a.w);
  r[4] = f2bf(b.x); r[5] = f2bf(b.y); r[6] = f2bf(b.z); r[7] = f2bf(b.w);
  return r;
}

__device__ __forceinline__ f32x4 mfma16(s8x8 a, s8x8 b, f32x4 c){
  return __builtin_amdgcn_mfma_f32_16x16x32_bf16(
      __builtin_bit_cast(bf8x8, a), __builtin_bit_cast(bf8x8, b), c, 0, 0, 0);
}

// Agent-scope relaxed load: bypasses (possibly stale) local L2, reads the
// L3/fabric coherence point. ONLY for cross-block buffers (Hcur, Cbuf).
__device__ __forceinline__ ull aload8(const short* p){
  return __hip_atomic_load((const ull*)p, __ATOMIC_RELAXED, __HIP_MEMORY_SCOPE_AGENT);
}

// Spread-arrival grid barrier: 16 one-shot counters per instance, each on its
// own 128-B line. Arrive: RELEASE agent fetch_add (dirty-line write-back, no
// invalidate). Wait: RELAXED 16-load poll.
// Layout: bar[inst*512 + g*32], inst in [0,40), g in [0,16).
__device__ __forceinline__ void grid_bar(unsigned* bar, int inst, int nblk){
  __syncthreads();
  if (threadIdx.x == 0){
    unsigned* base = bar + inst*512;
    int g = blockIdx.x & 15;
    __hip_atomic_fetch_add(base + g*32, 1u, __ATOMIC_RELEASE, __HIP_MEMORY_SCOPE_AGENT);
    for (;;){
      unsigned s = 0;
      #pragma unroll
      for (int i = 0; i < 16; i++)
        s += __hip_atomic_load(base + i*32, __ATOMIC_RELAXED, __HIP_MEMORY_SCOPE_AGENT);
      if (s >= (unsigned)nblk) break;
      __builtin_amdgcn_s_sleep(4);
    }
  }
  __syncthreads();
}

// ---------------------------------------------------------------------------
// One-time prepack (unchanged, proven): wcatp gate-packed bf16, whp bf16 Wh.
// ---------------------------------------------------------------------------
__global__ __launch_bounds__(256) void k_prep2(
    const float* __restrict__ Whh, const float* __restrict__ Wih,
    const float* __restrict__ Wh,
    short* __restrict__ wcatp, short* __restrict__ whp)
{
  const long CW = 393216;  // 2048*1536/8
  const long CH = 32768;   // 512*512/8
  for (long c = blockIdx.x*256L + threadIdx.x; c < CW + CH; c += (long)gridDim.x*256L){
    if (c < CW){
      long s = c*8;
      int jt = (int)(s / 196608);
      int r  = (int)(s % 196608);
      int it = r >> 13;
      int r2 = r & 8191;
      int row = r2 >> 6, kk = r2 & 63;
      int jg = ((row>>5)<<9) + jt*32 + (row&31);
      int k = it*64 + kk;
      const float* src = (k < 512) ? (Whh + (long)jg*512 + k)
                                   : (Wih + (long)jg*1024 + (k - 512));
      *(s8x8*)(wcatp + s) = cast8(src);
    } else {
      long j = (c - CW)*8;
      *(s8x8*)(whp + j) = cast8(Wh + j);
    }
  }
}

__global__ __launch_bounds__(256) void k_packout(const float* __restrict__ Wout,
                                                 short* __restrict__ woutbf)
{
  for (long c = blockIdx.x*256L + threadIdx.x; c < 640000; c += (long)gridDim.x*256L)
    *(s8x8*)(woutbf + c*8) = cast8(Wout + c*8);
}

// ---------------------------------------------------------------------------
// fvp = img @ Wv^T + att_b[r%49]  (bf16 out). Proven template. grid (4,49).
// ---------------------------------------------------------------------------
__global__ __launch_bounds__(256) void k_fv(const float* __restrict__ img,
    const float* __restrict__ Wv, const float* __restrict__ attb,
    short* __restrict__ fvbf)
{
  const int n0 = blockIdx.x*128, m0 = blockIdx.y*128;
  __shared__ short As[128*40];
  __shared__ short Bs[128*40];
  const int tid = threadIdx.x, w = tid>>6, lane = tid&63;
  f32x4 acc[8][2] = {};
  for (int k0 = 0; k0 < 512; k0 += 32){
    for (int c = tid; c < 512; c += 256){
      int row = c>>2, ko = (c&3)*8;
      *(s8x8*)(As + row*40 + ko) = cast8(img + (long)(m0+row)*512 + k0 + ko);
      *(s8x8*)(Bs + row*40 + ko) = cast8(Wv  + (long)(n0+row)*512 + k0 + ko);
    }
    __syncthreads();
    const int kb = (lane>>4)*8, l15 = lane&15;
    s8x8 b0f = *(const s8x8*)(Bs + (w*32 + l15)*40 + kb);
    s8x8 b1f = *(const s8x8*)(Bs + (w*32 + 16 + l15)*40 + kb);
    #pragma unroll
    for (int mt = 0; mt < 8; mt++){
      s8x8 a = *(const s8x8*)(As + (mt*16 + l15)*40 + kb);
      acc[mt][0] = mfma16(a, b0f, acc[mt][0]);
      acc[mt][1] = mfma16(a, b1f, acc[mt][1]);
    }
    __syncthreads();
  }
  const int l15 = lane&15;
  #pragma unroll
  for (int mt = 0; mt < 8; mt++){
    int rb = m0 + mt*16 + ((lane>>4)<<2);
    #pragma unroll
    for (int nt = 0; nt < 2; nt++){
      int cg = n0 + w*32 + nt*16 + l15;
      #pragma unroll
      for (int rr = 0; rr < 4; rr++){
        int r = rb + rr;
        fvbf[(long)r*512 + cg] = f2bf(acc[mt][nt][rr] + attb[r % NN]);
      }
    }
  }
}

// ---------------------------------------------------------------------------
// Persistent kernel: ENTIRE 20-step recurrence, 128 blocks x 256 threads.
// R13: GAT decode jt = bid&15, bt = bid>>4 (was jt = bid>>3). With round-robin
// bid->XCD, each XCD now touches only 2 wcatp slices (786 KB) instead of all
// 16 (6.3 MB) -> per-XCD L2 working set ~3.7 MB < 4 MB (was 9.2 MB, thrash).
// Everything else identical to R12 (proven absmax 4.88e-4).
// ---------------------------------------------------------------------------
__global__ __launch_bounds__(256) void k_loop(
    const short* __restrict__ whp, const short* __restrict__ fvbf,
    const float* __restrict__ Wa, const float* __restrict__ img,
    const short* __restrict__ wcatp, const float* __restrict__ embed,
    const int* __restrict__ caps, const float* __restrict__ bih,
    const float* __restrict__ bhh, short* __restrict__ Hbuf,
    short* __restrict__ Cbuf, float* __restrict__ cst,
    short* __restrict__ Hall, float* __restrict__ alph,
    unsigned* __restrict__ bar)
{
  __shared__ float hs[512];
  __shared__ float ohs[512];
  __shared__ float ee[64];
  __shared__ float zp[4][512];
  __shared__ short xs[16][1024];   // GAT: h|ctx for this block's 16 batches
  __shared__ short As[16*76];
  __shared__ short Bs[128*76];
  __shared__ float gs[16][132];

  const int bid = blockIdx.x, tid = threadIdx.x;
  const int w = tid>>6, lane = tid&63;

  for (int t = 0; t < TT; t++){
    const short* Hcur = Hbuf + (t&1)*65536;
    short*       Hnxt = Hbuf + ((t+1)&1)*65536;

    // ================= ATT phase (b = bid) =================
    {
      const int b = bid;
      if (t == 0){
        for (int d = tid; d < 512; d += 256){
          float s = 0.f;
          for (int n = 0; n < NN; n++) s += img[((long)b*NN + n)*512 + d];
          Cbuf[b*512 + d] = f2bf(s * (1.f/49.f));
        }
        if (tid < NN) alph[((long)b*NN + tid)*TT] = 0.f;
      } else {
        // stage h (cross-block, written by GAT last step) via agent loads
        for (int i = tid; i < 128; i += 256){
          ull u = aload8(Hcur + (long)b*512 + i*4);
          short4 sv = __builtin_bit_cast(short4, u);
          hs[i*4+0] = bf2f(sv.x); hs[i*4+1] = bf2f(sv.y);
          hs[i*4+2] = bf2f(sv.z); hs[i*4+3] = bf2f(sv.w);
        }
        __syncthreads();
        for (int d = tid; d < 512; d += 256){
          const short* wr = whp + (long)d*512;
          float s = 0.f;
          for (int j8 = 0; j8 < 512; j8 += 8){
            s8x8 v = *(const s8x8*)(wr + j8);
            #pragma unroll
            for (int q = 0; q < 8; q++) s = fmaf(hs[j8+q], bf2f(v[q]), s);
          }
          ohs[d] = s;
        }
        __syncthreads();
        float ohr[8], war[8];
        {
          const float* wp = Wa + lane*8;
          #pragma unroll
          for (int q = 0; q < 8; q++){ ohr[q] = ohs[lane*8 + q]; war[q] = wp[q]; }
        }
        for (int n = w; n < NN; n += 4){
          s8x8 v = *(const s8x8*)(fvbf + ((long)b*NN + n)*512 + lane*8);
          float s = 0.f;
          #pragma unroll
          for (int q = 0; q < 8; q++)
            s = fmaf(fmaxf(bf2f(v[q]) + ohr[q], 0.f), war[q], s);
          #pragma unroll
          for (int off = 32; off; off >>= 1) s += __shfl_xor(s, off);
          if (lane == 0) ee[n] = s;
        }
        __syncthreads();
        if (tid < 64){
          float e = (tid < NN) ? ee[tid] : -1e30f;
          float m = e;
          #pragma unroll
          for (int off = 32; off; off >>= 1) m = fmaxf(m, __shfl_xor(m, off));
          float ex = (tid < NN) ? __expf(e - m) : 0.f;
          float s = ex;
          #pragma unroll
          for (int off = 32; off; off >>= 1) s += __shfl_xor(s, off);
          float a = ex / s;
          if (tid < NN){ ee[tid] = a; alph[((long)b*NN + tid)*TT + t] = a; }
        }
        __syncthreads();
        const int cq = tid>>6, d0 = (tid&63)*8;
        float z[8] = {0,0,0,0,0,0,0,0};
        for (int n = cq; n < NN; n += 4){
          float an = ee[n];
          const float* ip = img + ((long)b*NN + n)*512 + d0;
          float4 u0 = *(const float4*)ip;
          float4 u1 = *(const float4*)(ip + 4);
          z[0] = fmaf(an, u0.x, z[0]); z[1] = fmaf(an, u0.y, z[1]);
          z[2] = fmaf(an, u0.z, z[2]); z[3] = fmaf(an, u0.w, z[3]);
          z[4] = fmaf(an, u1.x, z[4]); z[5] = fmaf(an, u1.y, z[5]);
          z[6] = fmaf(an, u1.z, z[6]); z[7] = fmaf(an, u1.w, z[7]);
        }
        #pragma unroll
        for (int q = 0; q < 8; q++) zp[cq][d0 + q] = z[q];
        __syncthreads();
        if (tid < 64){
          int dd = tid*8;
          s8x8 o;
          #pragma unroll
          for (int q = 0; q < 8; q++)
            o[q] = f2bf(zp[0][dd+q] + zp[1][dd+q] + zp[2][dd+q] + zp[3][dd+q]);
          *(s8x8*)(Cbuf + b*512 + dd) = o;
        }
      }
    }
    grid_bar(bar, 2*t, 128);

    // ======== GAT phase (R13: jt = bid&15 -> XCD-local wcatp slice) ========
    {
      const int jt = bid & 15, b0 = (bid >> 4)*16;
      const int J0 = jt*32;
      const long wbase = (long)jt*24*8192;

      // Stage h|ctx for 16 batches into LDS (agent loads, cross-block).
      for (int i = tid; i < 4096; i += 256){
        int bl = i >> 8, q = (i & 255)*4;
        ull u = 0;
        if (q < 512){
          if (t != 0) u = aload8(Hcur + (long)(b0+bl)*512 + q);
        } else {
          u = aload8(Cbuf + (long)(b0+bl)*512 + (q - 512));
        }
        *(ull*)(&xs[bl][q]) = u;
      }
      __syncthreads();

      s8x8 a_r, b_r[4];
      auto stage_load = [&](int it){
        if (tid < 128){
          int row = tid>>3, kkc = (tid&7)*8;
          int k = it*64 + kkc;
          s8x8 av;
          if (k < 1024) av = *(const s8x8*)(&xs[row][k]);
          else av = cast8(embed + (long)caps[(b0+row)*TT + t]*512 + (k - 1024));
          a_r = av;
        }
        #pragma unroll
        for (int i = 0; i < 4; i++){
          long c = tid + i*256;
          b_r[i] = *(const s8x8*)(wcatp + wbase + (long)it*8192 + c*8);
        }
      };

      f32x4 acc[2] = {};
      stage_load(0);
      for (int it = 0; it < 24; ++it){
        if (tid < 128)
          *(s8x8*)(As + (tid>>3)*76 + (tid&7)*8) = a_r;
        #pragma unroll
        for (int i = 0; i < 4; i++){
          int c = tid + i*256;
          *(s8x8*)(Bs + (c>>3)*76 + (c&7)*8) = b_r[i];
        }
        __syncthreads();
        if (it < 23) stage_load(it + 1);
        const int kb = (lane>>4)*8, l15 = lane&15, cw = w*32;
        #pragma unroll
        for (int ks = 0; ks < 2; ks++){
          s8x8 b0f = *(const s8x8*)(Bs + (cw + l15)*76 + kb + ks*32);
          s8x8 b1f = *(const s8x8*)(Bs + (cw + 16 + l15)*76 + kb + ks*32);
          s8x8 a = *(const s8x8*)(As + l15*76 + kb + ks*32);
          acc[0] = mfma16(a, b0f, acc[0]);
          acc[1] = mfma16(a, b1f, acc[1]);
        }
        __syncthreads();
      }
      {
        const int l15 = lane&15;
        int rl = (lane>>4)<<2;
        #pragma unroll
        for (int nt = 0; nt < 2; nt++){
          int ct = w*32 + nt*16 + l15;
          #pragma unroll
          for (int rr = 0; rr < 4; rr++)
            gs[rl+rr][ct] = acc[nt][rr];
        }
      }
      __syncthreads();
      for (int task = tid; task < 512; task += 256){
        int bl = task>>5, jc = task&31;
        int gb = b0 + bl, j = J0 + jc;
        float gi = gs[bl][jc]      + bih[j]        + bhh[j];
        float gf = gs[bl][32+jc]   + bih[512+j]    + bhh[512+j];
        float gg = gs[bl][64+jc]   + bih[1024+j]   + bhh[1024+j];
        float go = gs[bl][96+jc]   + bih[1536+j]   + bhh[1536+j];
        float ii = 1.f/(1.f+__expf(-gi));
        float ff = 1.f/(1.f+__expf(-gf));
        float e2 = __expf(2.f*gg); float g2 = (e2-1.f)/(e2+1.f);
        float oo = 1.f/(1.f+__expf(-go));
        float cp = (t == 0) ? 0.f : cst[gb*512 + j];
        float cN = ff*cp + ii*g2;
        float e3 = __expf(2.f*cN); float th = (e3-1.f)/(e3+1.f);
        float hN = oo*th;
        cst[gb*512 + j] = cN;
        short hb = f2bf(hN);
        Hnxt[gb*512 + j] = hb;
        Hall[((long)gb*TT + t)*512 + j] = hb;
      }
    }
    grid_bar(bar, 2*t + 1, 128);
  }
}

// ---------------------------------------------------------------------------
// Final GEMM: preds = Hall(bf16) @ woutbf(bf16)^T + bout.
// Proven template + XCD-bijective block remap.
// ---------------------------------------------------------------------------
__global__ __launch_bounds__(256) void k_out(const short* __restrict__ Abf,
    const short* __restrict__ Bbf, float* __restrict__ outf,
    const float* __restrict__ bias)
{
  int flat = blockIdx.y*79 + blockIdx.x;
  int xcd = flat & 7, idx = flat >> 3;
  int wg = (xcd < 4) ? xcd*198 + idx : 792 + (xcd-4)*197 + idx;
  const int n0 = (wg/20)*128, m0 = (wg%20)*128;
  __shared__ short As[128*40];
  __shared__ short Bs[128*40];
  const int tid = threadIdx.x, w = tid>>6, lane = tid&63;
  f32x4 acc[8][2] = {};
  for (int k0 = 0; k0 < 512; k0 += 32){
    for (int c = tid; c < 512; c += 256){
      int row = c>>2, ko = (c&3)*8;
      *(s8x8*)(As + row*40 + ko) = *(const s8x8*)(Abf + (long)(m0+row)*512 + k0 + ko);
      int brow = n0 + row;
      s8x8 bv = {0,0,0,0,0,0,0,0};
      if (brow < VV) bv = *(const s8x8*)(Bbf + (long)brow*512 + k0 + ko);
      *(s8x8*)(Bs + row*40 + ko) = bv;
    }
    __syncthreads();
    const int kb = (lane>>4)*8, l15 = lane&15;
    s8x8 b0f = *(const s8x8*)(Bs + (w*32 + l15)*40 + kb);
    s8x8 b1f = *(const s8x8*)(Bs + (w*32 + 16 + l15)*40 + kb);
    #pragma unroll
    for (int mt = 0; mt < 8; mt++){
      s8x8 a = *(const s8x8*)(As + (mt*16 + l15)*40 + kb);
      acc[mt][0] = mfma16(a, b0f, acc[mt][0]);
      acc[mt][1] = mfma16(a, b1f, acc[mt][1]);
    }
    __syncthreads();
  }
  const int l15 = lane&15;
  #pragma unroll
  for (int mt = 0; mt < 8; mt++){
    int rb = m0 + mt*16 + ((lane>>4)<<2);
    #pragma unroll
    for (int nt = 0; nt < 2; nt++){
      int cg = n0 + w*32 + nt*16 + l15;
      if (cg >= VV) continue;
      #pragma unroll
      for (int rr = 0; rr < 4; rr++){
        int r = rb + rr;
        outf[(long)r*VV + cg] = acc[mt][nt][rr] + bias[cg];
      }
    }
  }
}

// ---------------------------------------------------------------------------
extern "C" void kernel_launch(void* const* d_in, const int* in_sizes, int n_in,
                              void* d_out, int out_size, void* d_ws, size_t ws_size,
                              hipStream_t stream)
{
  const float* img  = (const float*)d_in[0];
  const int*   caps = (const int*)d_in[1];
  const float* emb  = (const float*)d_in[2];
  const float* Wv   = (const float*)d_in[3];
  const float* Wh   = (const float*)d_in[4];
  const float* attb = (const float*)d_in[5];
  const float* Wa   = (const float*)d_in[6];
  const float* Wih  = (const float*)d_in[7];
  const float* bih  = (const float*)d_in[8];
  const float* Whh  = (const float*)d_in[9];
  const float* bhh  = (const float*)d_in[10];
  const float* Wout = (const float*)d_in[11];
  const float* bout = (const float*)d_in[12];
  float* preds = (float*)d_out;
  float* alph  = preds + (long)BB*TT*VV;

  // Workspace layout: 16,777,216 B total (proven available).
  char* ws = (char*)d_ws;
  short* wcatp  = (short*)(ws);              // 6,291,456 B
  short* whp    = (short*)(ws + 6291456);    //   524,288 B
  short* fvbf   = (short*)(ws + 6815744);    // 6,422,528 B
  short* Hbuf   = (short*)(ws + 13238272);   //   262,144 B (2 x [128][512] bf16)
  short* Cbuf   = (short*)(ws + 13500416);   //   131,072 B
  float* cst    = (float*)(ws + 13631488);   //   262,144 B
  short* Hall   = (short*)(ws + 13893632);   // 2,621,440 B -> 16,515,072
  unsigned* bar = (unsigned*)(ws + 16515072);// 81,920 B: 40 inst x 16 ctrs x 128B
  short* woutbf = (short*)(ws);              // alias (dead after t-loop)

  hipMemsetAsync(bar, 0, 81920, stream);  // reset barrier counters every call
  k_prep2<<<1024, 256, 0, stream>>>(Whh, Wih, Wh, wcatp, whp);
  k_fv<<<dim3(4,49), 256, 0, stream>>>(img, Wv, attb, fvbf);

  k_loop<<<128, 256, 0, stream>>>(whp, fvbf, Wa, img, wcatp, emb, caps,
                                  bih, bhh, Hbuf, Cbuf, cst, Hall, alph, bar);

  k_packout<<<1024, 256, 0, stream>>>(Wout, woutbf);
  k_out<<<dim3(79,20), 256, 0, stream>>>(Hall, woutbf, preds, bout);
}

// Round 14
// 1153.566 us; speedup vs baseline: 1.1105x; 1.1105x over previous
//
#include <hip/hip_runtime.h>
#include <hip/hip_bf16.h>

#define BB 128
#define NN 49
#define VV 10000
#define TT 20

typedef short s8x8 __attribute__((ext_vector_type(8)));
typedef __bf16 bf8x8 __attribute__((ext_vector_type(8)));
typedef float f32x4 __attribute__((ext_vector_type(4)));
typedef unsigned long long ull;
typedef ull ull2 __attribute__((ext_vector_type(2)));

__device__ __forceinline__ float bf2f(short s){ return (float)__builtin_bit_cast(__bf16, s); }
__device__ __forceinline__ short f2bf(float f){ return __builtin_bit_cast(short, (__bf16)f); }

__device__ __forceinline__ s8x8 cast8(const float* p){
  float4 a = *(const float4*)p;
  float4 b = *(const float4*)(p + 4);
  s8x8 r;
  r[0] = f2bf(a.x); r[1] = f2bf(a.y); r[2] = f2bf(a.z); r[3] = f2bf(a.w);
  r[4] = f2bf(b.x); r[5] = f2bf(b.y); r[6] = f2bf(b.z); r[7] = f2bf(b.w);
  return r;
}

__device__ __forceinline__ f32x4 mfma16(s8x8 a, s8x8 b, f32x4 c){
  return __builtin_amdgcn_mfma_f32_16x16x32_bf16(
      __builtin_bit_cast(bf8x8, a), __builtin_bit_cast(bf8x8, b), c, 0, 0, 0);
}

// Agent-scope relaxed load: bypasses (possibly stale) local L2, reads the
// L3/fabric coherence point. Used for cross-block-read buffers (Hcur, Cbuf).
__device__ __forceinline__ ull aload8(const short* p){
  return __hip_atomic_load((const ull*)p, __ATOMIC_RELAXED, __HIP_MEMORY_SCOPE_AGENT);
}
// Agent-scope relaxed store: write-through to L3 coherence point (no dirty
// L2 line -> no wbl2 needed anywhere). Used for cross-block-written buffers.
__device__ __forceinline__ void astore8(short* p, ull v){
  __hip_atomic_store((ull*)p, v, __ATOMIC_RELAXED, __HIP_MEMORY_SCOPE_AGENT);
}

// R14 grid barrier: NO release/acquire anywhere -> no buffer_wbl2 L2 tag-walk
// (theory: that walk was ~20 us/barrier in R11-R13). Data visibility comes
// from write-through astore8 + the vmcnt(0) drain __syncthreads performs
// before s_barrier (compiler-verified), so a RELAXED arrival add suffices.
// 16 spread counters on separate 128-B lines; one-shot per instance.
__device__ __forceinline__ void grid_bar(unsigned* bar, int inst, int nblk){
  __syncthreads();   // drains each wave's vmcnt -> all astore8 acked at L3
  if (threadIdx.x == 0){
    unsigned* base = bar + inst*512;
    int g = blockIdx.x & 15;
    __hip_atomic_fetch_add(base + g*32, 1u, __ATOMIC_RELAXED, __HIP_MEMORY_SCOPE_AGENT);
    for (;;){
      unsigned s = 0;
      #pragma unroll
      for (int i = 0; i < 16; i++)
        s += __hip_atomic_load(base + i*32, __ATOMIC_RELAXED, __HIP_MEMORY_SCOPE_AGENT);
      if (s >= (unsigned)nblk) break;
      __builtin_amdgcn_s_sleep(4);
    }
  }
  __syncthreads();
}

// ---------------------------------------------------------------------------
// One-time prepack (unchanged, proven): wcatp gate-packed bf16, whp bf16 Wh.
// ---------------------------------------------------------------------------
__global__ __launch_bounds__(256) void k_prep2(
    const float* __restrict__ Whh, const float* __restrict__ Wih,
    const float* __restrict__ Wh,
    short* __restrict__ wcatp, short* __restrict__ whp)
{
  const long CW = 393216;  // 2048*1536/8
  const long CH = 32768;   // 512*512/8
  for (long c = blockIdx.x*256L + threadIdx.x; c < CW + CH; c += (long)gridDim.x*256L){
    if (c < CW){
      long s = c*8;
      int jt = (int)(s / 196608);
      int r  = (int)(s % 196608);
      int it = r >> 13;
      int r2 = r & 8191;
      int row = r2 >> 6, kk = r2 & 63;
      int jg = ((row>>5)<<9) + jt*32 + (row&31);
      int k = it*64 + kk;
      const float* src = (k < 512) ? (Whh + (long)jg*512 + k)
                                   : (Wih + (long)jg*1024 + (k - 512));
      *(s8x8*)(wcatp + s) = cast8(src);
    } else {
      long j = (c - CW)*8;
      *(s8x8*)(whp + j) = cast8(Wh + j);
    }
  }
}

__global__ __launch_bounds__(256) void k_packout(const float* __restrict__ Wout,
                                                 short* __restrict__ woutbf)
{
  for (long c = blockIdx.x*256L + threadIdx.x; c < 640000; c += (long)gridDim.x*256L)
    *(s8x8*)(woutbf + c*8) = cast8(Wout + c*8);
}

// ---------------------------------------------------------------------------
// fvp = img @ Wv^T + att_b[r%49]  (bf16 out). Proven template. grid (4,49).
// ---------------------------------------------------------------------------
__global__ __launch_bounds__(256) void k_fv(const float* __restrict__ img,
    const float* __restrict__ Wv, const float* __restrict__ attb,
    short* __restrict__ fvbf)
{
  const int n0 = blockIdx.x*128, m0 = blockIdx.y*128;
  __shared__ short As[128*40];
  __shared__ short Bs[128*40];
  const int tid = threadIdx.x, w = tid>>6, lane = tid&63;
  f32x4 acc[8][2] = {};
  for (int k0 = 0; k0 < 512; k0 += 32){
    for (int c = tid; c < 512; c += 256){
      int row = c>>2, ko = (c&3)*8;
      *(s8x8*)(As + row*40 + ko) = cast8(img + (long)(m0+row)*512 + k0 + ko);
      *(s8x8*)(Bs + row*40 + ko) = cast8(Wv  + (long)(n0+row)*512 + k0 + ko);
    }
    __syncthreads();
    const int kb = (lane>>4)*8, l15 = lane&15;
    s8x8 b0f = *(const s8x8*)(Bs + (w*32 + l15)*40 + kb);
    s8x8 b1f = *(const s8x8*)(Bs + (w*32 + 16 + l15)*40 + kb);
    #pragma unroll
    for (int mt = 0; mt < 8; mt++){
      s8x8 a = *(const s8x8*)(As + (mt*16 + l15)*40 + kb);
      acc[mt][0] = mfma16(a, b0f, acc[mt][0]);
      acc[mt][1] = mfma16(a, b1f, acc[mt][1]);
    }
    __syncthreads();
  }
  const int l15 = lane&15;
  #pragma unroll
  for (int mt = 0; mt < 8; mt++){
    int rb = m0 + mt*16 + ((lane>>4)<<2);
    #pragma unroll
    for (int nt = 0; nt < 2; nt++){
      int cg = n0 + w*32 + nt*16 + l15;
      #pragma unroll
      for (int rr = 0; rr < 4; rr++){
        int r = rb + rr;
        fvbf[(long)r*512 + cg] = f2bf(acc[mt][nt][rr] + attb[r % NN]);
      }
    }
  }
}

// ---------------------------------------------------------------------------
// Persistent kernel: ENTIRE 20-step recurrence, 128 blocks x 256 threads.
// R14: no-release barriers (no wbl2); cross-block data written via agent
// write-through atomic stores, read via agent loads. GAT decode = R12's
// (jt = bid>>3, b0 = (bid&7)*16; cst lines 128-B aligned block-private).
// Phase arithmetic bit-identical to R7/R12 (proven absmax 4.88e-4).
// ---------------------------------------------------------------------------
__global__ __launch_bounds__(256) void k_loop(
    const short* __restrict__ whp, const short* __restrict__ fvbf,
    const float* __restrict__ Wa, const float* __restrict__ img,
    const short* __restrict__ wcatp, const float* __restrict__ embed,
    const int* __restrict__ caps, const float* __restrict__ bih,
    const float* __restrict__ bhh, short* __restrict__ Hbuf,
    short* __restrict__ Cbuf, float* __restrict__ cst,
    short* __restrict__ Hall, float* __restrict__ alph,
    unsigned* __restrict__ bar)
{
  __shared__ float hs[512];
  __shared__ float ohs[512];
  __shared__ float ee[64];
  __shared__ float zp[4][512];
  __shared__ short xs[16][1024];   // GAT: h|ctx for this block's 16 batches
  __shared__ short As[16*76];
  __shared__ short Bs[128*76];
  __shared__ float gs[16][132];
  __shared__ short hsb[16][32];    // GAT: h_t staging for packed Hnxt stores

  const int bid = blockIdx.x, tid = threadIdx.x;
  const int w = tid>>6, lane = tid&63;

  for (int t = 0; t < TT; t++){
    const short* Hcur = Hbuf + (t&1)*65536;
    short*       Hnxt = Hbuf + ((t+1)&1)*65536;

    // ================= ATT phase (b = bid) =================
    {
      const int b = bid;
      if (t == 0){
        for (int d = tid; d < 512; d += 256){
          float s = 0.f;
          for (int n = 0; n < NN; n++) s += img[((long)b*NN + n)*512 + d];
          zp[0][d] = s * (1.f/49.f);
        }
        __syncthreads();
        if (tid < 64){
          int dd = tid*8;
          s8x8 o;
          #pragma unroll
          for (int q = 0; q < 8; q++) o[q] = f2bf(zp[0][dd+q]);
          ull2 u = __builtin_bit_cast(ull2, o);
          astore8(Cbuf + b*512 + dd, u.x);
          astore8(Cbuf + b*512 + dd + 4, u.y);
        }
        if (tid < NN) alph[((long)b*NN + tid)*TT] = 0.f;
      } else {
        // stage h (cross-block, written by GAT last step) via agent loads
        for (int i = tid; i < 128; i += 256){
          ull u = aload8(Hcur + (long)b*512 + i*4);
          short4 sv = __builtin_bit_cast(short4, u);
          hs[i*4+0] = bf2f(sv.x); hs[i*4+1] = bf2f(sv.y);
          hs[i*4+2] = bf2f(sv.z); hs[i*4+3] = bf2f(sv.w);
        }
        __syncthreads();
        for (int d = tid; d < 512; d += 256){
          const short* wr = whp + (long)d*512;
          float s = 0.f;
          for (int j8 = 0; j8 < 512; j8 += 8){
            s8x8 v = *(const s8x8*)(wr + j8);
            #pragma unroll
            for (int q = 0; q < 8; q++) s = fmaf(hs[j8+q], bf2f(v[q]), s);
          }
          ohs[d] = s;
        }
        __syncthreads();
        float ohr[8], war[8];
        {
          const float* wp = Wa + lane*8;
          #pragma unroll
          for (int q = 0; q < 8; q++){ ohr[q] = ohs[lane*8 + q]; war[q] = wp[q]; }
        }
        for (int n = w; n < NN; n += 4){
          s8x8 v = *(const s8x8*)(fvbf + ((long)b*NN + n)*512 + lane*8);
          float s = 0.f;
          #pragma unroll
          for (int q = 0; q < 8; q++)
            s = fmaf(fmaxf(bf2f(v[q]) + ohr[q], 0.f), war[q], s);
          #pragma unroll
          for (int off = 32; off; off >>= 1) s += __shfl_xor(s, off);
          if (lane == 0) ee[n] = s;
        }
        __syncthreads();
        if (tid < 64){
          float e = (tid < NN) ? ee[tid] : -1e30f;
          float m = e;
          #pragma unroll
          for (int off = 32; off; off >>= 1) m = fmaxf(m, __shfl_xor(m, off));
          float ex = (tid < NN) ? __expf(e - m) : 0.f;
          float s = ex;
          #pragma unroll
          for (int off = 32; off; off >>= 1) s += __shfl_xor(s, off);
          float a = ex / s;
          if (tid < NN){ ee[tid] = a; alph[((long)b*NN + tid)*TT + t] = a; }
        }
        __syncthreads();
        const int cq = tid>>6, d0 = (tid&63)*8;
        float z[8] = {0,0,0,0,0,0,0,0};
        for (int n = cq; n < NN; n += 4){
          float an = ee[n];
          const float* ip = img + ((long)b*NN + n)*512 + d0;
          float4 u0 = *(const float4*)ip;
          float4 u1 = *(const float4*)(ip + 4);
          z[0] = fmaf(an, u0.x, z[0]); z[1] = fmaf(an, u0.y, z[1]);
          z[2] = fmaf(an, u0.z, z[2]); z[3] = fmaf(an, u0.w, z[3]);
          z[4] = fmaf(an, u1.x, z[4]); z[5] = fmaf(an, u1.y, z[5]);
          z[6] = fmaf(an, u1.z, z[6]); z[7] = fmaf(an, u1.w, z[7]);
        }
        #pragma unroll
        for (int q = 0; q < 8; q++) zp[cq][d0 + q] = z[q];
        __syncthreads();
        if (tid < 64){
          int dd = tid*8;
          s8x8 o;
          #pragma unroll
          for (int q = 0; q < 8; q++)
            o[q] = f2bf(zp[0][dd+q] + zp[1][dd+q] + zp[2][dd+q] + zp[3][dd+q]);
          ull2 u = __builtin_bit_cast(ull2, o);
          astore8(Cbuf + b*512 + dd, u.x);
          astore8(Cbuf + b*512 + dd + 4, u.y);
        }
      }
    }
    grid_bar(bar, 2*t, 128);

    // ================= GAT phase (jt = bid>>3, bt = bid&7) =================
    {
      const int jt = bid >> 3, b0 = (bid & 7)*16;
      const int J0 = jt*32;
      const long wbase = (long)jt*24*8192;

      // Stage h|ctx for 16 batches into LDS (agent loads, cross-block).
      for (int i = tid; i < 4096; i += 256){
        int bl = i >> 8, q = (i & 255)*4;
        ull u = 0;
        if (q < 512){
          if (t != 0) u = aload8(Hcur + (long)(b0+bl)*512 + q);
        } else {
          u = aload8(Cbuf + (long)(b0+bl)*512 + (q - 512));
        }
        *(ull*)(&xs[bl][q]) = u;
      }
      __syncthreads();

      s8x8 a_r, b_r[4];
      auto stage_load = [&](int it){
        if (tid < 128){
          int row = tid>>3, kkc = (tid&7)*8;
          int k = it*64 + kkc;
          s8x8 av;
          if (k < 1024) av = *(const s8x8*)(&xs[row][k]);
          else av = cast8(embed + (long)caps[(b0+row)*TT + t]*512 + (k - 1024));
          a_r = av;
        }
        #pragma unroll
        for (int i = 0; i < 4; i++){
          long c = tid + i*256;
          b_r[i] = *(const s8x8*)(wcatp + wbase + (long)it*8192 + c*8);
        }
      };

      f32x4 acc[2] = {};
      stage_load(0);
      for (int it = 0; it < 24; ++it){
        if (tid < 128)
          *(s8x8*)(As + (tid>>3)*76 + (tid&7)*8) = a_r;
        #pragma unroll
        for (int i = 0; i < 4; i++){
          int c = tid + i*256;
          *(s8x8*)(Bs + (c>>3)*76 + (c&7)*8) = b_r[i];
        }
        __syncthreads();
        if (it < 23) stage_load(it + 1);
        const int kb = (lane>>4)*8, l15 = lane&15, cw = w*32;
        #pragma unroll
        for (int ks = 0; ks < 2; ks++){
          s8x8 b0f = *(const s8x8*)(Bs + (cw + l15)*76 + kb + ks*32);
          s8x8 b1f = *(const s8x8*)(Bs + (cw + 16 + l15)*76 + kb + ks*32);
          s8x8 a = *(const s8x8*)(As + l15*76 + kb + ks*32);
          acc[0] = mfma16(a, b0f, acc[0]);
          acc[1] = mfma16(a, b1f, acc[1]);
        }
        __syncthreads();
      }
      {
        const int l15 = lane&15;
        int rl = (lane>>4)<<2;
        #pragma unroll
        for (int nt = 0; nt < 2; nt++){
          int ct = w*32 + nt*16 + l15;
          #pragma unroll
          for (int rr = 0; rr < 4; rr++)
            gs[rl+rr][ct] = acc[nt][rr];
        }
      }
      __syncthreads();
      for (int task = tid; task < 512; task += 256){
        int bl = task>>5, jc = task&31;
        int gb = b0 + bl, j = J0 + jc;
        float gi = gs[bl][jc]      + bih[j]        + bhh[j];
        float gf = gs[bl][32+jc]   + bih[512+j]    + bhh[512+j];
        float gg = gs[bl][64+jc]   + bih[1024+j]   + bhh[1024+j];
        float go = gs[bl][96+jc]   + bih[1536+j]   + bhh[1536+j];
        float ii = 1.f/(1.f+__expf(-gi));
        float ff = 1.f/(1.f+__expf(-gf));
        float e2 = __expf(2.f*gg); float g2 = (e2-1.f)/(e2+1.f);
        float oo = 1.f/(1.f+__expf(-go));
        float cp = (t == 0) ? 0.f : cst[gb*512 + j];
        float cN = ff*cp + ii*g2;
        float e3 = __expf(2.f*cN); float th = (e3-1.f)/(e3+1.f);
        float hN = oo*th;
        cst[gb*512 + j] = cN;                       // block-private line, plain
        short hb = f2bf(hN);
        hsb[bl][jc] = hb;                           // stage for packed astore
        Hall[((long)gb*TT + t)*512 + j] = hb;       // post-kernel reader, plain
      }
      __syncthreads();
      if (tid < 128){
        int row = tid>>3, c4 = (tid&7)*4;
        ull u = *(const ull*)(&hsb[row][c4]);
        astore8(Hnxt + (long)(b0+row)*512 + J0 + c4, u);
      }
    }
    grid_bar(bar, 2*t + 1, 128);
  }
}

// ---------------------------------------------------------------------------
// Final GEMM: preds = Hall(bf16) @ woutbf(bf16)^T + bout.
// Proven template + XCD-bijective block remap.
// ---------------------------------------------------------------------------
__global__ __launch_bounds__(256) void k_out(const short* __restrict__ Abf,
    const short* __restrict__ Bbf, float* __restrict__ outf,
    const float* __restrict__ bias)
{
  int flat = blockIdx.y*79 + blockIdx.x;
  int xcd = flat & 7, idx = flat >> 3;
  int wg = (xcd < 4) ? xcd*198 + idx : 792 + (xcd-4)*197 + idx;
  const int n0 = (wg/20)*128, m0 = (wg%20)*128;
  __shared__ short As[128*40];
  __shared__ short Bs[128*40];
  const int tid = threadIdx.x, w = tid>>6, lane = tid&63;
  f32x4 acc[8][2] = {};
  for (int k0 = 0; k0 < 512; k0 += 32){
    for (int c = tid; c < 512; c += 256){
      int row = c>>2, ko = (c&3)*8;
      *(s8x8*)(As + row*40 + ko) = *(const s8x8*)(Abf + (long)(m0+row)*512 + k0 + ko);
      int brow = n0 + row;
      s8x8 bv = {0,0,0,0,0,0,0,0};
      if (brow < VV) bv = *(const s8x8*)(Bbf + (long)brow*512 + k0 + ko);
      *(s8x8*)(Bs + row*40 + ko) = bv;
    }
    __syncthreads();
    const int kb = (lane>>4)*8, l15 = lane&15;
    s8x8 b0f = *(const s8x8*)(Bs + (w*32 + l15)*40 + kb);
    s8x8 b1f = *(const s8x8*)(Bs + (w*32 + 16 + l15)*40 + kb);
    #pragma unroll
    for (int mt = 0; mt < 8; mt++){
      s8x8 a = *(const s8x8*)(As + (mt*16 + l15)*40 + kb);
      acc[mt][0] = mfma16(a, b0f, acc[mt][0]);
      acc[mt][1] = mfma16(a, b1f, acc[mt][1]);
    }
    __syncthreads();
  }
  const int l15 = lane&15;
  #pragma unroll
  for (int mt = 0; mt < 8; mt++){
    int rb = m0 + mt*16 + ((lane>>4)<<2);
    #pragma unroll
    for (int nt = 0; nt < 2; nt++){
      int cg = n0 + w*32 + nt*16 + l15;
      if (cg >= VV) continue;
      #pragma unroll
      for (int rr = 0; rr < 4; rr++){
        int r = rb + rr;
        outf[(long)r*VV + cg] = acc[mt][nt][rr] + bias[cg];
      }
    }
  }
}

// ---------------------------------------------------------------------------
extern "C" void kernel_launch(void* const* d_in, const int* in_sizes, int n_in,
                              void* d_out, int out_size, void* d_ws, size_t ws_size,
                              hipStream_t stream)
{
  const float* img  = (const float*)d_in[0];
  const int*   caps = (const int*)d_in[1];
  const float* emb  = (const float*)d_in[2];
  const float* Wv   = (const float*)d_in[3];
  const float* Wh   = (const float*)d_in[4];
  const float* attb = (const float*)d_in[5];
  const float* Wa   = (const float*)d_in[6];
  const float* Wih  = (const float*)d_in[7];
  const float* bih  = (const float*)d_in[8];
  const float* Whh  = (const float*)d_in[9];
  const float* bhh  = (const float*)d_in[10];
  const float* Wout = (const float*)d_in[11];
  const float* bout = (const float*)d_in[12];
  float* preds = (float*)d_out;
  float* alph  = preds + (long)BB*TT*VV;

  // Workspace layout: 16,777,216 B total (proven available).
  char* ws = (char*)d_ws;
  short* wcatp  = (short*)(ws);              // 6,291,456 B
  short* whp    = (short*)(ws + 6291456);    //   524,288 B
  short* fvbf   = (short*)(ws + 6815744);    // 6,422,528 B
  short* Hbuf   = (short*)(ws + 13238272);   //   262,144 B (2 x [128][512] bf16)
  short* Cbuf   = (short*)(ws + 13500416);   //   131,072 B
  float* cst    = (float*)(ws + 13631488);   //   262,144 B
  short* Hall   = (short*)(ws + 13893632);   // 2,621,440 B -> 16,515,072
  unsigned* bar = (unsigned*)(ws + 16515072);// 81,920 B: 40 inst x 16 ctrs x 128B
  short* woutbf = (short*)(ws);              // alias (dead after t-loop)

  hipMemsetAsync(bar, 0, 81920, stream);  // reset barrier counters every call
  k_prep2<<<1024, 256, 0, stream>>>(Whh, Wih, Wh, wcatp, whp);
  k_fv<<<dim3(4,49), 256, 0, stream>>>(img, Wv, attb, fvbf);

  k_loop<<<128, 256, 0, stream>>>(whp, fvbf, Wa, img, wcatp, emb, caps,
                                  bih, bhh, Hbuf, Cbuf, cst, Hall, alph, bar);

  k_packout<<<1024, 256, 0, stream>>>(Wout, woutbf);
  k_out<<<dim3(79,20), 256, 0, stream>>>(Hall, woutbf, preds, bout);
}

// Round 15
// 1015.595 us; speedup vs baseline: 1.2613x; 1.1359x over previous
//
#include <hip/hip_runtime.h>
#include <hip/hip_bf16.h>

#define BB 128
#define NN 49
#define VV 10000
#define TT 20

typedef short s8x8 __attribute__((ext_vector_type(8)));
typedef __bf16 bf8x8 __attribute__((ext_vector_type(8)));
typedef float f32x4 __attribute__((ext_vector_type(4)));
typedef unsigned long long ull;
typedef ull ull2 __attribute__((ext_vector_type(2)));

__device__ __forceinline__ float bf2f(short s){ return (float)__builtin_bit_cast(__bf16, s); }
__device__ __forceinline__ short f2bf(float f){ return __builtin_bit_cast(short, (__bf16)f); }

__device__ __forceinline__ s8x8 cast8(const float* p){
  float4 a = *(const float4*)p;
  float4 b = *(const float4*)(p + 4);
  s8x8 r;
  r[0] = f2bf(a.x); r[1] = f2bf(a.y); r[2] = f2bf(a.z); r[3] = f2bf(a.w);
  r[4] = f2bf(b.x); r[5] = f2bf(b.y); r[6] = f2bf(b.z); r[7] = f2bf(b.w);
  return r;
}

__device__ __forceinline__ f32x4 mfma16(s8x8 a, s8x8 b, f32x4 c){
  return __builtin_amdgcn_mfma_f32_16x16x32_bf16(
      __builtin_bit_cast(bf8x8, a), __builtin_bit_cast(bf8x8, b), c, 0, 0, 0);
}

// Agent-scope relaxed load/store: bypass local L2, hit the L3 coherence
// point. Used ONLY for the intra-kernel Cbuf handoff (R14-proven).
__device__ __forceinline__ ull aload8(const short* p){
  return __hip_atomic_load((const ull*)p, __ATOMIC_RELAXED, __HIP_MEMORY_SCOPE_AGENT);
}
__device__ __forceinline__ void astore8(short* p, ull v){
  __hip_atomic_store((ull*)p, v, __ATOMIC_RELAXED, __HIP_MEMORY_SCOPE_AGENT);
}

// Relaxed spread-arrival grid barrier (R14-proven at 128 blocks).
// Data visibility: astore8 write-through + vmcnt drain at __syncthreads.
__device__ __forceinline__ void grid_bar(unsigned* bar, int inst, int nblk){
  __syncthreads();
  if (threadIdx.x == 0){
    unsigned* base = bar + inst*512;
    int g = blockIdx.x & 15;
    __hip_atomic_fetch_add(base + g*32, 1u, __ATOMIC_RELAXED, __HIP_MEMORY_SCOPE_AGENT);
    for (;;){
      unsigned s = 0;
      #pragma unroll
      for (int i = 0; i < 16; i++)
        s += __hip_atomic_load(base + i*32, __ATOMIC_RELAXED, __HIP_MEMORY_SCOPE_AGENT);
      if (s >= (unsigned)nblk) break;
      __builtin_amdgcn_s_sleep(4);
    }
  }
  __syncthreads();
}

// ---------------------------------------------------------------------------
// One-time prepack (proven): wcatp gate-packed bf16, whp bf16 Wh.
// ---------------------------------------------------------------------------
__global__ __launch_bounds__(256) void k_prep2(
    const float* __restrict__ Whh, const float* __restrict__ Wih,
    const float* __restrict__ Wh,
    short* __restrict__ wcatp, short* __restrict__ whp)
{
  const long CW = 393216;  // 2048*1536/8
  const long CH = 32768;   // 512*512/8
  for (long c = blockIdx.x*256L + threadIdx.x; c < CW + CH; c += (long)gridDim.x*256L){
    if (c < CW){
      long s = c*8;
      int jt = (int)(s / 196608);
      int r  = (int)(s % 196608);
      int it = r >> 13;
      int r2 = r & 8191;
      int row = r2 >> 6, kk = r2 & 63;
      int jg = ((row>>5)<<9) + jt*32 + (row&31);
      int k = it*64 + kk;
      const float* src = (k < 512) ? (Whh + (long)jg*512 + k)
                                   : (Wih + (long)jg*1024 + (k - 512));
      *(s8x8*)(wcatp + s) = cast8(src);
    } else {
      long j = (c - CW)*8;
      *(s8x8*)(whp + j) = cast8(Wh + j);
    }
  }
}

__global__ __launch_bounds__(256) void k_packout(const float* __restrict__ Wout,
                                                 short* __restrict__ woutbf)
{
  for (long c = blockIdx.x*256L + threadIdx.x; c < 640000; c += (long)gridDim.x*256L)
    *(s8x8*)(woutbf + c*8) = cast8(Wout + c*8);
}

// ---------------------------------------------------------------------------
// fvp = img @ Wv^T + att_b[r%49]  (bf16 out). Proven template. grid (4,49).
// ---------------------------------------------------------------------------
__global__ __launch_bounds__(256) void k_fv(const float* __restrict__ img,
    const float* __restrict__ Wv, const float* __restrict__ attb,
    short* __restrict__ fvbf)
{
  const int n0 = blockIdx.x*128, m0 = blockIdx.y*128;
  __shared__ short As[128*40];
  __shared__ short Bs[128*40];
  const int tid = threadIdx.x, w = tid>>6, lane = tid&63;
  f32x4 acc[8][2] = {};
  for (int k0 = 0; k0 < 512; k0 += 32){
    for (int c = tid; c < 512; c += 256){
      int row = c>>2, ko = (c&3)*8;
      *(s8x8*)(As + row*40 + ko) = cast8(img + (long)(m0+row)*512 + k0 + ko);
      *(s8x8*)(Bs + row*40 + ko) = cast8(Wv  + (long)(n0+row)*512 + k0 + ko);
    }
    __syncthreads();
    const int kb = (lane>>4)*8, l15 = lane&15;
    s8x8 b0f = *(const s8x8*)(Bs + (w*32 + l15)*40 + kb);
    s8x8 b1f = *(const s8x8*)(Bs + (w*32 + 16 + l15)*40 + kb);
    #pragma unroll
    for (int mt = 0; mt < 8; mt++){
      s8x8 a = *(const s8x8*)(As + (mt*16 + l15)*40 + kb);
      acc[mt][0] = mfma16(a, b0f, acc[mt][0]);
      acc[mt][1] = mfma16(a, b1f, acc[mt][1]);
    }
    __syncthreads();
  }
  const int l15 = lane&15;
  #pragma unroll
  for (int mt = 0; mt < 8; mt++){
    int rb = m0 + mt*16 + ((lane>>4)<<2);
    #pragma unroll
    for (int nt = 0; nt < 2; nt++){
      int cg = n0 + w*32 + nt*16 + l15;
      #pragma unroll
      for (int rr = 0; rr < 4; rr++){
        int r = rb + rr;
        fvbf[(long)r*512 + cg] = f2bf(acc[mt][nt][rr] + attb[r % NN]);
      }
    }
  }
}

// ---------------------------------------------------------------------------
// ONE STEP per dispatch: ATT phase (b = bid) -> grid_bar -> GAT phase
// (jt = bid>>3, bt = bid&7). h crosses KERNEL boundaries (implicit
// coherence); ctx (Cbuf) crosses the intra-kernel barrier via astore/aload
// (R14-proven). GAT weight stream prefetched 2-deep; GAT's h-half of xs
// pre-staged before ATT to overlap latency. Arithmetic verbatim R7/R14.
// ---------------------------------------------------------------------------
__global__ __launch_bounds__(256) void k_step(
    const short* __restrict__ whp, const short* __restrict__ fvbf,
    const float* __restrict__ Wa, const float* __restrict__ img,
    const short* __restrict__ wcatp, const float* __restrict__ embed,
    const int* __restrict__ caps, const float* __restrict__ bih,
    const float* __restrict__ bhh, short* __restrict__ Hbuf,
    short* __restrict__ Cbuf, float* __restrict__ cst,
    short* __restrict__ Hall, float* __restrict__ alph,
    unsigned* __restrict__ bar, int t)
{
  __shared__ float hs[512];
  __shared__ float ohs[512];
  __shared__ float ee[64];
  __shared__ float zp[4][512];
  __shared__ short xs[16][1024];
  __shared__ short As[16*76];
  __shared__ short Bs[128*76];
  __shared__ float gs[16][132];

  const int bid = blockIdx.x, tid = threadIdx.x;
  const int w = tid>>6, lane = tid&63;
  const short* Hcur = Hbuf + (t&1)*65536;
  short*       Hnxt = Hbuf + ((t+1)&1)*65536;

  // --- Pre-stage GAT's h-half of xs (plain loads; prev-kernel coherent) ---
  {
    const int b0g = (bid & 7)*16;
    for (int i = tid; i < 2048; i += 256){
      int bl = i >> 7, q = (i & 127)*4;
      ull u = 0;
      if (t != 0) u = *(const ull*)(Hcur + (long)(b0g+bl)*512 + q);
      *(ull*)(&xs[bl][q]) = u;
    }
  }

  // ========================= ATT phase (b = bid) =========================
  {
    const int b = bid;
    if (t == 0){
      for (int d = tid; d < 512; d += 256){
        float s = 0.f;
        for (int n = 0; n < NN; n++) s += img[((long)b*NN + n)*512 + d];
        zp[0][d] = s * (1.f/49.f);
      }
      __syncthreads();
      if (tid < 64){
        int dd = tid*8;
        s8x8 o;
        #pragma unroll
        for (int q = 0; q < 8; q++) o[q] = f2bf(zp[0][dd+q]);
        ull2 u = __builtin_bit_cast(ull2, o);
        astore8(Cbuf + b*512 + dd, u.x);
        astore8(Cbuf + b*512 + dd + 4, u.y);
      }
      if (tid < NN) alph[((long)b*NN + tid)*TT] = 0.f;
    } else {
      for (int d = tid; d < 512; d += 256) hs[d] = bf2f(Hcur[b*512 + d]);
      __syncthreads();
      for (int d = tid; d < 512; d += 256){
        const short* wr = whp + (long)d*512;
        float s = 0.f;
        for (int j8 = 0; j8 < 512; j8 += 8){
          s8x8 v = *(const s8x8*)(wr + j8);
          #pragma unroll
          for (int q = 0; q < 8; q++) s = fmaf(hs[j8+q], bf2f(v[q]), s);
        }
        ohs[d] = s;
      }
      __syncthreads();
      float ohr[8], war[8];
      {
        const float* wp = Wa + lane*8;
        #pragma unroll
        for (int q = 0; q < 8; q++){ ohr[q] = ohs[lane*8 + q]; war[q] = wp[q]; }
      }
      for (int n = w; n < NN; n += 4){
        s8x8 v = *(const s8x8*)(fvbf + ((long)b*NN + n)*512 + lane*8);
        float s = 0.f;
        #pragma unroll
        for (int q = 0; q < 8; q++)
          s = fmaf(fmaxf(bf2f(v[q]) + ohr[q], 0.f), war[q], s);
        #pragma unroll
        for (int off = 32; off; off >>= 1) s += __shfl_xor(s, off);
        if (lane == 0) ee[n] = s;
      }
      __syncthreads();
      if (tid < 64){
        float e = (tid < NN) ? ee[tid] : -1e30f;
        float m = e;
        #pragma unroll
        for (int off = 32; off; off >>= 1) m = fmaxf(m, __shfl_xor(m, off));
        float ex = (tid < NN) ? __expf(e - m) : 0.f;
        float s = ex;
        #pragma unroll
        for (int off = 32; off; off >>= 1) s += __shfl_xor(s, off);
        float a = ex / s;
        if (tid < NN){ ee[tid] = a; alph[((long)b*NN + tid)*TT + t] = a; }
      }
      __syncthreads();
      const int cq = tid>>6, d0 = (tid&63)*8;
      float z[8] = {0,0,0,0,0,0,0,0};
      for (int n = cq; n < NN; n += 4){
        float an = ee[n];
        const float* ip = img + ((long)b*NN + n)*512 + d0;
        float4 u0 = *(const float4*)ip;
        float4 u1 = *(const float4*)(ip + 4);
        z[0] = fmaf(an, u0.x, z[0]); z[1] = fmaf(an, u0.y, z[1]);
        z[2] = fmaf(an, u0.z, z[2]); z[3] = fmaf(an, u0.w, z[3]);
        z[4] = fmaf(an, u1.x, z[4]); z[5] = fmaf(an, u1.y, z[5]);
        z[6] = fmaf(an, u1.z, z[6]); z[7] = fmaf(an, u1.w, z[7]);
      }
      #pragma unroll
      for (int q = 0; q < 8; q++) zp[cq][d0 + q] = z[q];
      __syncthreads();
      if (tid < 64){
        int dd = tid*8;
        s8x8 o;
        #pragma unroll
        for (int q = 0; q < 8; q++)
          o[q] = f2bf(zp[0][dd+q] + zp[1][dd+q] + zp[2][dd+q] + zp[3][dd+q]);
        ull2 u = __builtin_bit_cast(ull2, o);
        astore8(Cbuf + b*512 + dd, u.x);
        astore8(Cbuf + b*512 + dd + 4, u.y);
      }
    }
  }
  grid_bar(bar, t, 128);

  // ================= GAT phase (jt = bid>>3, bt = bid&7) =================
  {
    const int jt = bid >> 3, b0 = (bid & 7)*16;
    const int J0 = jt*32;
    const long wbase = (long)jt*24*8192;

    // Stage ctx half of xs (cross-block within this kernel -> agent loads).
    for (int i = tid; i < 2048; i += 256){
      int bl = i >> 7, q = (i & 127)*4;
      ull u = aload8(Cbuf + (long)(b0+bl)*512 + q);
      *(ull*)(&xs[bl][512 + q]) = u;
    }
    __syncthreads();

    auto lda = [&](int it) -> s8x8 {
      s8x8 av = {0,0,0,0,0,0,0,0};
      if (tid < 128){
        int row = tid>>3, kkc = (tid&7)*8;
        int k = it*64 + kkc;
        if (k < 1024) av = *(const s8x8*)(&xs[row][k]);
        else av = cast8(embed + (long)caps[(b0+row)*TT + t]*512 + (k - 1024));
      }
      return av;
    };
    auto ldb = [&](int it, s8x8* br){
      #pragma unroll
      for (int i = 0; i < 4; i++){
        long c = tid + i*256;
        br[i] = *(const s8x8*)(wcatp + wbase + (long)it*8192 + c*8);
      }
    };
    auto put = [&](s8x8 av, const s8x8* br){
      if (tid < 128)
        *(s8x8*)(As + (tid>>3)*76 + (tid&7)*8) = av;
      #pragma unroll
      for (int i = 0; i < 4; i++){
        int c = tid + i*256;
        *(s8x8*)(Bs + (c>>3)*76 + (c&7)*8) = br[i];
      }
    };

    f32x4 acc[2] = {};
    const int kb = (lane>>4)*8, l15 = lane&15, cw = w*32;
    auto mmas = [&](){
      #pragma unroll
      for (int ks = 0; ks < 2; ks++){
        s8x8 b0f = *(const s8x8*)(Bs + (cw + l15)*76 + kb + ks*32);
        s8x8 b1f = *(const s8x8*)(Bs + (cw + 16 + l15)*76 + kb + ks*32);
        s8x8 a = *(const s8x8*)(As + l15*76 + kb + ks*32);
        acc[0] = mfma16(a, b0f, acc[0]);
        acc[1] = mfma16(a, b1f, acc[1]);
      }
    };

    // 2-deep software pipeline over 24 K-iterations (explicit ping-pong).
    s8x8 a0 = lda(0), a1 = lda(1), b0r[4], b1r[4];
    ldb(0, b0r); ldb(1, b1r);
    for (int it2 = 0; it2 < 24; it2 += 2){
      put(a0, b0r);
      __syncthreads();
      if (it2 + 2 < 24){ a0 = lda(it2+2); ldb(it2+2, b0r); }
      mmas();
      __syncthreads();
      put(a1, b1r);
      __syncthreads();
      if (it2 + 3 < 24){ a1 = lda(it2+3); ldb(it2+3, b1r); }
      mmas();
      __syncthreads();
    }
    {
      int rl = (lane>>4)<<2;
      #pragma unroll
      for (int nt = 0; nt < 2; nt++){
        int ct = cw + nt*16 + l15;
        #pragma unroll
        for (int rr = 0; rr < 4; rr++)
          gs[rl+rr][ct] = acc[nt][rr];
      }
    }
    __syncthreads();
    for (int task = tid; task < 512; task += 256){
      int bl = task>>5, jc = task&31;
      int gb = b0 + bl, j = J0 + jc;
      float gi = gs[bl][jc]      + bih[j]        + bhh[j];
      float gf = gs[bl][32+jc]   + bih[512+j]    + bhh[512+j];
      float gg = gs[bl][64+jc]   + bih[1024+j]   + bhh[1024+j];
      float go = gs[bl][96+jc]   + bih[1536+j]   + bhh[1536+j];
      float ii = 1.f/(1.f+__expf(-gi));
      float ff = 1.f/(1.f+__expf(-gf));
      float e2 = __expf(2.f*gg); float g2 = (e2-1.f)/(e2+1.f);
      float oo = 1.f/(1.f+__expf(-go));
      float cp = (t == 0) ? 0.f : cst[gb*512 + j];
      float cN = ff*cp + ii*g2;
      float e3 = __expf(2.f*cN); float th = (e3-1.f)/(e3+1.f);
      float hN = oo*th;
      cst[gb*512 + j] = cN;
      short hb = f2bf(hN);
      Hnxt[gb*512 + j] = hb;                 // next kernel reads (boundary flush)
      Hall[((long)gb*TT + t)*512 + j] = hb;  // k_out reads (boundary flush)
    }
  }
}

// ---------------------------------------------------------------------------
// Final GEMM: preds = Hall(bf16) @ woutbf(bf16)^T + bout.
// Proven template + XCD-bijective block remap.
// ---------------------------------------------------------------------------
__global__ __launch_bounds__(256) void k_out(const short* __restrict__ Abf,
    const short* __restrict__ Bbf, float* __restrict__ outf,
    const float* __restrict__ bias)
{
  int flat = blockIdx.y*79 + blockIdx.x;
  int xcd = flat & 7, idx = flat >> 3;
  int wg = (xcd < 4) ? xcd*198 + idx : 792 + (xcd-4)*197 + idx;
  const int n0 = (wg/20)*128, m0 = (wg%20)*128;
  __shared__ short As[128*40];
  __shared__ short Bs[128*40];
  const int tid = threadIdx.x, w = tid>>6, lane = tid&63;
  f32x4 acc[8][2] = {};
  for (int k0 = 0; k0 < 512; k0 += 32){
    for (int c = tid; c < 512; c += 256){
      int row = c>>2, ko = (c&3)*8;
      *(s8x8*)(As + row*40 + ko) = *(const s8x8*)(Abf + (long)(m0+row)*512 + k0 + ko);
      int brow = n0 + row;
      s8x8 bv = {0,0,0,0,0,0,0,0};
      if (brow < VV) bv = *(const s8x8*)(Bbf + (long)brow*512 + k0 + ko);
      *(s8x8*)(Bs + row*40 + ko) = bv;
    }
    __syncthreads();
    const int kb = (lane>>4)*8, l15 = lane&15;
    s8x8 b0f = *(const s8x8*)(Bs + (w*32 + l15)*40 + kb);
    s8x8 b1f = *(const s8x8*)(Bs + (w*32 + 16 + l15)*40 + kb);
    #pragma unroll
    for (int mt = 0; mt < 8; mt++){
      s8x8 a = *(const s8x8*)(As + (mt*16 + l15)*40 + kb);
      acc[mt][0] = mfma16(a, b0f, acc[mt][0]);
      acc[mt][1] = mfma16(a, b1f, acc[mt][1]);
    }
    __syncthreads();
  }
  const int l15 = lane&15;
  #pragma unroll
  for (int mt = 0; mt < 8; mt++){
    int rb = m0 + mt*16 + ((lane>>4)<<2);
    #pragma unroll
    for (int nt = 0; nt < 2; nt++){
      int cg = n0 + w*32 + nt*16 + l15;
      if (cg >= VV) continue;
      #pragma unroll
      for (int rr = 0; rr < 4; rr++){
        int r = rb + rr;
        outf[(long)r*VV + cg] = acc[mt][nt][rr] + bias[cg];
      }
    }
  }
}

// ---------------------------------------------------------------------------
extern "C" void kernel_launch(void* const* d_in, const int* in_sizes, int n_in,
                              void* d_out, int out_size, void* d_ws, size_t ws_size,
                              hipStream_t stream)
{
  const float* img  = (const float*)d_in[0];
  const int*   caps = (const int*)d_in[1];
  const float* emb  = (const float*)d_in[2];
  const float* Wv   = (const float*)d_in[3];
  const float* Wh   = (const float*)d_in[4];
  const float* attb = (const float*)d_in[5];
  const float* Wa   = (const float*)d_in[6];
  const float* Wih  = (const float*)d_in[7];
  const float* bih  = (const float*)d_in[8];
  const float* Whh  = (const float*)d_in[9];
  const float* bhh  = (const float*)d_in[10];
  const float* Wout = (const float*)d_in[11];
  const float* bout = (const float*)d_in[12];
  float* preds = (float*)d_out;
  float* alph  = preds + (long)BB*TT*VV;

  // Workspace layout: 16,777,216 + 81,920 B (proven available).
  char* ws = (char*)d_ws;
  short* wcatp  = (short*)(ws);              // 6,291,456 B
  short* whp    = (short*)(ws + 6291456);    //   524,288 B
  short* fvbf   = (short*)(ws + 6815744);    // 6,422,528 B
  short* Hbuf   = (short*)(ws + 13238272);   //   262,144 B (2 x [128][512] bf16)
  short* Cbuf   = (short*)(ws + 13500416);   //   131,072 B
  float* cst    = (float*)(ws + 13631488);   //   262,144 B
  short* Hall   = (short*)(ws + 13893632);   // 2,621,440 B -> 16,515,072
  unsigned* bar = (unsigned*)(ws + 16515072);// 40 KiB: 20 inst x 16 ctrs x 128B
  short* woutbf = (short*)(ws);              // alias (dead after t-loop)

  hipMemsetAsync(bar, 0, 81920, stream);
  k_prep2<<<1024, 256, 0, stream>>>(Whh, Wih, Wh, wcatp, whp);
  k_fv<<<dim3(4,49), 256, 0, stream>>>(img, Wv, attb, fvbf);

  for (int t = 0; t < TT; t++)
    k_step<<<128, 256, 0, stream>>>(whp, fvbf, Wa, img, wcatp, emb, caps,
                                    bih, bhh, Hbuf, Cbuf, cst, Hall, alph,
                                    bar, t);

  k_packout<<<1024, 256, 0, stream>>>(Wout, woutbf);
  k_out<<<dim3(79,20), 256, 0, stream>>>(Hall, woutbf, preds, bout);
}